// Round 1
// baseline (520.917 us; speedup 1.0000x reference)
//
#include <hip/hip_runtime.h>
#include <math.h>

// (32, 3, 1024, 1024) fp32, 8x8 window max/min pool -> 20*ln(max/(min+eps))
// masked by (max != min), summed, scaled by w*w/(H*W)/B -> scalar.
//
// Lane-pair layout for fully coalesced loads:
//   thread t loads float4 column index t of each row (unit stride across the
//   wave: 256 threads x 16B = one full 4KiB image row per load instruction).
//   Lane pair (2k, 2k+1) covers window k's 8 columns; one __shfl_xor(1)
//   merges the two half-window max/min. Both lanes add the halved log term
//   (exact in fp32), avoiding divergence.
// Block = 256 threads handles 16 image rows (2 window-rows) of one plane.

#define IMG_ROWS 1024
#define IMG_COLS 1024
#define F4_PER_ROW (IMG_COLS / 4)   // 256
#define WIN 8
#define NPLANE (32 * 3)

__global__ __launch_bounds__(256) void eme_window_kernel(
    const float* __restrict__ in, float* __restrict__ out) {
    const int blk   = blockIdx.x;       // 0 .. NPLANE*64 - 1
    const int band  = blk & 63;         // 64 bands of 16 image rows each
    const int plane = blk >> 6;         // b*3 + c
    const int tid   = threadIdx.x;      // = float4 column index, 0..255

    const float4* pbase = (const float4*)(in) +
                          (size_t)plane * IMG_ROWS * F4_PER_ROW;

    float sum = 0.0f;
#pragma unroll
    for (int wr = 0; wr < 2; ++wr) {
        const int row0 = band * 16 + wr * WIN;
        const float4* rp = pbase + (size_t)row0 * F4_PER_ROW + tid;

        float4 a = rp[0];
        float mx = fmaxf(fmaxf(a.x, a.y), fmaxf(a.z, a.w));
        float mn = fminf(fminf(a.x, a.y), fminf(a.z, a.w));
#pragma unroll
        for (int r = 1; r < WIN; ++r) {
            float4 v = rp[(size_t)r * F4_PER_ROW];
            mx = fmaxf(mx, fmaxf(fmaxf(v.x, v.y), fmaxf(v.z, v.w)));
            mn = fminf(mn, fminf(fminf(v.x, v.y), fminf(v.z, v.w)));
        }

        // merge the two half-windows held by the lane pair
        mx = fmaxf(mx, __shfl_xor(mx, 1, 64));
        mn = fminf(mn, __shfl_xor(mn, 1, 64));

        if (mx - mn != 0.0f) {
            // both lanes of the pair add half the window's contribution
            sum += 10.0f * logf(mx / (mn + 1e-4f));   // 20 * 0.5
        }
    }

    // wave (64-lane) shuffle reduction
#pragma unroll
    for (int off = 32; off > 0; off >>= 1) {
        sum += __shfl_down(sum, off, 64);
    }

    __shared__ float wsum[4];
    const int lane = tid & 63;
    const int wave = tid >> 6;
    if (lane == 0) wsum[wave] = sum;
    __syncthreads();
    if (tid == 0) {
        float s = wsum[0] + wsum[1] + wsum[2] + wsum[3];
        const float scale = (float)(WIN * WIN) /
                            ((float)IMG_ROWS * (float)IMG_COLS) / 32.0f;
        atomicAdd(out, s * scale);
    }
}

extern "C" void kernel_launch(void* const* d_in, const int* in_sizes, int n_in,
                              void* d_out, int out_size, void* d_ws, size_t ws_size,
                              hipStream_t stream) {
    const float* y_pred = (const float*)d_in[0];
    float* out = (float*)d_out;

    // d_out is poisoned to 0xAA before every timed launch — zero it on-stream.
    hipMemsetAsync(out, 0, sizeof(float), stream);

    const int grid = NPLANE * 64;  // 6144 blocks x 256 threads
    eme_window_kernel<<<grid, 256, 0, stream>>>(y_pred, out);
}

// Round 2
// 517.534 us; speedup vs baseline: 1.0065x; 1.0065x over previous
//
#include <hip/hip_runtime.h>
#include <math.h>

// (32, 3, 1024, 1024) fp32, 8x8 window max/min pool -> 20*ln(max/(min+eps))
// masked by (max != min), summed, scaled by w*w/(H*W)/B -> scalar.
//
// Two-stage reduction: stage 1 computes per-block sums with NO atomics
// (plain store of one float per block into d_ws); stage 2 (one block)
// reduces the 6144 partials and writes the scaled scalar. This removes
// the 6144 same-address atomicAdd serialization tail (~100cy each RMW,
// dependent chain in TCC) that capped the previous version at ~1.5 TB/s.
//
// Load layout (kept from R1, fully coalesced): thread t loads float4
// column index t of each row; lane pair (2k,2k+1) covers window k's 8
// columns; one __shfl_xor(1) merges; both lanes add the halved log term.

#define IMG_ROWS 1024
#define IMG_COLS 1024
#define F4_PER_ROW (IMG_COLS / 4)   // 256
#define WIN 8
#define NPLANE (32 * 3)
#define NBLK (NPLANE * 64)          // 6144 stage-1 blocks

__global__ __launch_bounds__(256) void eme_window_kernel(
    const float* __restrict__ in, float* __restrict__ partial) {
    const int blk   = blockIdx.x;       // 0 .. NBLK-1
    const int band  = blk & 63;         // 64 bands of 16 image rows each
    const int plane = blk >> 6;         // b*3 + c
    const int tid   = threadIdx.x;      // = float4 column index, 0..255

    const float4* pbase = (const float4*)(in) +
                          (size_t)plane * IMG_ROWS * F4_PER_ROW;

    float sum = 0.0f;
#pragma unroll
    for (int wr = 0; wr < 2; ++wr) {
        const int row0 = band * 16 + wr * WIN;
        const float4* rp = pbase + (size_t)row0 * F4_PER_ROW + tid;

        float4 a = rp[0];
        float mx = fmaxf(fmaxf(a.x, a.y), fmaxf(a.z, a.w));
        float mn = fminf(fminf(a.x, a.y), fminf(a.z, a.w));
#pragma unroll
        for (int r = 1; r < WIN; ++r) {
            float4 v = rp[(size_t)r * F4_PER_ROW];
            mx = fmaxf(mx, fmaxf(fmaxf(v.x, v.y), fmaxf(v.z, v.w)));
            mn = fminf(mn, fminf(fminf(v.x, v.y), fminf(v.z, v.w)));
        }

        // merge the two half-windows held by the lane pair
        mx = fmaxf(mx, __shfl_xor(mx, 1, 64));
        mn = fminf(mn, __shfl_xor(mn, 1, 64));

        if (mx - mn != 0.0f) {
            // both lanes of the pair add half the window's contribution
            sum += 10.0f * logf(mx / (mn + 1e-4f));   // 20 * 0.5
        }
    }

    // wave (64-lane) shuffle reduction
#pragma unroll
    for (int off = 32; off > 0; off >>= 1) {
        sum += __shfl_down(sum, off, 64);
    }

    __shared__ float wsum[4];
    const int lane = tid & 63;
    const int wave = tid >> 6;
    if (lane == 0) wsum[wave] = sum;
    __syncthreads();
    if (tid == 0) {
        partial[blk] = wsum[0] + wsum[1] + wsum[2] + wsum[3];
    }
}

__global__ __launch_bounds__(256) void eme_reduce_kernel(
    const float* __restrict__ partial, float* __restrict__ out) {
    float s = 0.0f;
    for (int i = threadIdx.x; i < NBLK; i += 256) {
        s += partial[i];
    }
#pragma unroll
    for (int off = 32; off > 0; off >>= 1) {
        s += __shfl_down(s, off, 64);
    }
    __shared__ float wsum[4];
    const int lane = threadIdx.x & 63;
    const int wave = threadIdx.x >> 6;
    if (lane == 0) wsum[wave] = s;
    __syncthreads();
    if (threadIdx.x == 0) {
        const float scale = (float)(WIN * WIN) /
                            ((float)IMG_ROWS * (float)IMG_COLS) / 32.0f;
        out[0] = (wsum[0] + wsum[1] + wsum[2] + wsum[3]) * scale;
    }
}

extern "C" void kernel_launch(void* const* d_in, const int* in_sizes, int n_in,
                              void* d_out, int out_size, void* d_ws, size_t ws_size,
                              hipStream_t stream) {
    const float* y_pred = (const float*)d_in[0];
    float* out = (float*)d_out;
    float* partial = (float*)d_ws;   // 6144 floats = 24 KB, all overwritten

    eme_window_kernel<<<NBLK, 256, 0, stream>>>(y_pred, partial);
    eme_reduce_kernel<<<1, 256, 0, stream>>>(partial, out);
}

// Round 3
// 490.795 us; speedup vs baseline: 1.0614x; 1.0545x over previous
//
#include <hip/hip_runtime.h>
#include <math.h>

// (32, 3, 1024, 1024) fp32, 8x8 window max/min pool -> 20*ln(max/(min+eps))
// masked by (max != min), summed, scaled by w*w/(H*W)/B -> scalar.
//
// R3 changes (theory: logf libm CALL was an MLP/scheduling barrier):
//  - all 16 row-loads issued up-front into registers (16 KB in flight/wave,
//    static indices after full unroll -> VGPRs, no scratch)
//  - __logf (inline v_log_f32-based) instead of the OCML logf call; rel err
//    ~1e-7 -> ~2e-5 absolute on the final scalar, negligible
//  - branchless: unconditional log + cndmask select, no divergence
//  - nontemporal load hints (read-once 402 MB stream, skip cache allocate)
//  - two-stage reduction kept (no atomics, stage 2 writes d_out directly)

#define IMG_ROWS 1024
#define IMG_COLS 1024
#define F4_PER_ROW (IMG_COLS / 4)   // 256
#define WIN 8
#define NPLANE (32 * 3)
#define NBLK (NPLANE * 64)          // 6144 stage-1 blocks

typedef float f4 __attribute__((ext_vector_type(4)));

__global__ __launch_bounds__(256) void eme_window_kernel(
    const float* __restrict__ in, float* __restrict__ partial) {
    const int blk   = blockIdx.x;       // 0 .. NBLK-1
    const int band  = blk & 63;         // 64 bands of 16 image rows each
    const int plane = blk >> 6;         // b*3 + c
    const int tid   = threadIdx.x;      // = float4 column index, 0..255

    const f4* rp = (const f4*)(in) +
                   (size_t)plane * IMG_ROWS * F4_PER_ROW +
                   (size_t)(band * 16) * F4_PER_ROW + tid;

    // issue ALL 16 row loads before any consumption: max MLP per wave
    f4 v[16];
#pragma unroll
    for (int r = 0; r < 16; ++r) {
        v[r] = __builtin_nontemporal_load(rp + (size_t)r * F4_PER_ROW);
    }

    float sum = 0.0f;
#pragma unroll
    for (int wr = 0; wr < 2; ++wr) {
        f4 a = v[wr * 8];
        float mx = fmaxf(fmaxf(a.x, a.y), fmaxf(a.z, a.w));
        float mn = fminf(fminf(a.x, a.y), fminf(a.z, a.w));
#pragma unroll
        for (int r = 1; r < 8; ++r) {
            f4 w = v[wr * 8 + r];
            mx = fmaxf(mx, fmaxf(fmaxf(w.x, w.y), fmaxf(w.z, w.w)));
            mn = fminf(mn, fminf(fminf(w.x, w.y), fminf(w.z, w.w)));
        }

        // merge the two half-windows held by the lane pair
        mx = fmaxf(mx, __shfl_xor(mx, 1, 64));
        mn = fminf(mn, __shfl_xor(mn, 1, 64));

        // branchless: both lanes of the pair add half the window's term
        float t = 10.0f * __logf(mx / (mn + 1e-4f));   // 20 * 0.5, inline log
        sum += (mx != mn) ? t : 0.0f;
    }

    // wave (64-lane) shuffle reduction
#pragma unroll
    for (int off = 32; off > 0; off >>= 1) {
        sum += __shfl_down(sum, off, 64);
    }

    __shared__ float wsum[4];
    const int lane = tid & 63;
    const int wave = tid >> 6;
    if (lane == 0) wsum[wave] = sum;
    __syncthreads();
    if (tid == 0) {
        partial[blk] = wsum[0] + wsum[1] + wsum[2] + wsum[3];
    }
}

__global__ __launch_bounds__(256) void eme_reduce_kernel(
    const float* __restrict__ partial, float* __restrict__ out) {
    float s = 0.0f;
    for (int i = threadIdx.x; i < NBLK; i += 256) {
        s += partial[i];
    }
#pragma unroll
    for (int off = 32; off > 0; off >>= 1) {
        s += __shfl_down(s, off, 64);
    }
    __shared__ float wsum[4];
    const int lane = threadIdx.x & 63;
    const int wave = threadIdx.x >> 6;
    if (lane == 0) wsum[wave] = s;
    __syncthreads();
    if (threadIdx.x == 0) {
        const float scale = (float)(WIN * WIN) /
                            ((float)IMG_ROWS * (float)IMG_COLS) / 32.0f;
        out[0] = (wsum[0] + wsum[1] + wsum[2] + wsum[3]) * scale;
    }
}

extern "C" void kernel_launch(void* const* d_in, const int* in_sizes, int n_in,
                              void* d_out, int out_size, void* d_ws, size_t ws_size,
                              hipStream_t stream) {
    const float* y_pred = (const float*)d_in[0];
    float* out = (float*)d_out;
    float* partial = (float*)d_ws;   // 6144 floats = 24 KB, all overwritten

    eme_window_kernel<<<NBLK, 256, 0, stream>>>(y_pred, partial);
    eme_reduce_kernel<<<1, 256, 0, stream>>>(partial, out);
}